// Round 13
// baseline (334.159 us; speedup 1.0000x reference)
//
#include <hip/hip_runtime.h>

constexpr int NN = 100000;
constexpr int NE = 1600000;
constexpr int NBUK = 196;            // 512-node buckets: 196*512 = 100352 >= NN
constexpr int ECAP = 10240;          // bucket capacity (E[cnt]=8192, sigma~90)
constexpr int CHUNK = 6250;          // edges per k_part1 block (256 blocks exact)
constexpr int NPT = 13;              // ceil(6250/512)

typedef __attribute__((ext_vector_type(8))) short bf16x8;
typedef __attribute__((ext_vector_type(4))) float f32x4;

__device__ inline ushort f2b(float f){
  uint u = __float_as_uint(f);
  uint r = (u + 0x7FFFu + ((u >> 16) & 1u)) >> 16;
  return (ushort)r;
}
__device__ inline float b2f(ushort u){
  uint v = ((uint)u) << 16;
  return __uint_as_float(v);
}

template<int CTRL>
__device__ inline float dpp_xadd(float v){
  int j = __builtin_amdgcn_update_dpp(0, __float_as_int(v), CTRL, 0xF, 0xF, true);
  return v + __int_as_float(j);
}
__device__ inline float red16(float v){
  v = dpp_xadd<0xB1>(v);
  v = dpp_xadd<0x4E>(v);
  v = dpp_xadd<0x141>(v);
  v = dpp_xadd<0x140>(v);
  return v;
}

// ---------------- CSR build, phase 1: block-local binning (+ xb convert tail) ----------------
__global__ __launch_bounds__(512) void k_part1(const int* __restrict__ srcA,
                                               const int* __restrict__ dstA,
                                               int* __restrict__ bukcur,
                                               int* __restrict__ ebuf,
                                               const float* __restrict__ x,
                                               ushort* __restrict__ xb){
  __shared__ int stage[CHUNK];
  __shared__ unsigned char bstage[CHUNK];
  __shared__ int hist[256];
  __shared__ int lofs[256];
  __shared__ int lcur[NBUK];
  __shared__ int basebuf[NBUK];
  int t = threadIdx.x;
  int cbase = blockIdx.x * CHUNK;

  if (t < 256) hist[t] = 0;
  if (t < NBUK) lcur[t] = 0;
  __syncthreads();

  int pk[NPT], bb[NPT];
  #pragma unroll
  for (int j = 0; j < NPT; ++j){
    int i = t + j*512;
    bb[j] = -1;
    if (i < CHUNK){
      int e = cbase + i;
      int d = dstA[e];
      bb[j] = d >> 9;
      pk[j] = (srcA[e] << 9) | (d & 511);
      atomicAdd(&hist[bb[j]], 1);
    }
  }
  __syncthreads();

  int v = (t < 256) ? hist[t] : 0;
  if (t < 256) lofs[t] = v;
  __syncthreads();
  #pragma unroll
  for (int off = 1; off < 256; off <<= 1){
    int tv = (t < 256 && t >= off) ? lofs[t-off] : 0;
    __syncthreads();
    if (t < 256) lofs[t] += tv;
    __syncthreads();
  }
  if (t < 256) lofs[t] -= v;
  if (t < NBUK) basebuf[t] = atomicAdd(&bukcur[t], v);
  __syncthreads();

  #pragma unroll
  for (int j = 0; j < NPT; ++j){
    if (bb[j] >= 0){
      int p = atomicAdd(&lcur[bb[j]], 1);
      int slot = lofs[bb[j]] + p;
      stage[slot] = pk[j];
      bstage[slot] = (unsigned char)bb[j];
    }
  }
  __syncthreads();

  for (int i = t; i < CHUNK; i += 512){
    int b = bstage[i];
    int j = i - lofs[b];
    int pos = basebuf[b] + j;
    if (pos < ECAP) ebuf[b*ECAP + pos] = stage[i];
  }

  // ---- tail: x -> bf16 (grid-stride over 1.6M float4), independent work ----
  for (int i = blockIdx.x*512 + t; i < NN*16; i += 256*512){
    float4 vv = ((const float4*)x)[i];
    ushort4 o;
    o.x = f2b(vv.x); o.y = f2b(vv.y); o.z = f2b(vv.z); o.w = f2b(vv.w);
    ((ushort4*)xb)[i] = o;
  }
}

// per bucket: LDS count -> scan -> rbeg/deg + compact csr into FIXED window b*ECAP
__global__ __launch_bounds__(512) void k_bfinal(const int* __restrict__ ebuf,
                                                const int* __restrict__ bukcur,
                                                int* __restrict__ rbeg,
                                                int* __restrict__ degA,
                                                int* __restrict__ csr){
  __shared__ int lcnt[512];
  __shared__ int lscan[512];
  __shared__ int lcur[512];
  int b = blockIdx.x, t = threadIdx.x;
  int cnt = bukcur[b]; if (cnt > ECAP) cnt = ECAP;
  int base = b*ECAP, gbase = b*ECAP;

  lcnt[t] = 0; lcur[t] = 0;
  __syncthreads();
  for (int i = t; i < cnt; i += 512) atomicAdd(&lcnt[ebuf[base+i] & 511], 1);
  __syncthreads();
  int v = lcnt[t];
  lscan[t] = v; __syncthreads();
  #pragma unroll
  for (int off = 1; off < 512; off <<= 1){
    int tv = (t >= off) ? lscan[t-off] : 0;
    __syncthreads();
    lscan[t] += tv;
    __syncthreads();
  }
  int excl = lscan[t] - v;
  lcnt[t] = excl;
  int node = b*512 + t;
  if (node < NN){ rbeg[node] = gbase + excl; degA[node] = v; }
  __syncthreads();
  for (int i = t; i < cnt; i += 512){
    int p = ebuf[base+i];
    int d = p & 511;
    int pos = atomicAdd(&lcur[d], 1);
    csr[gbase + lcnt[d] + pos] = p >> 9;
  }
}

// ---------------- effective-weight prep ----------------
__global__ void k_vchain(const float* __restrict__ Wp, float* __restrict__ V2,
                         float* __restrict__ V3){
  __shared__ float sA[4096], sB[4096], sC[4096];
  int t = threadIdx.x;
  for (int i = t; i < 4096; i += 256){ sA[i] = Wp[i]; sB[i] = Wp[4096+i]; }
  __syncthreads();
  for (int i = t; i < 4096; i += 256){
    int r = i >> 6, c = i & 63; float s = 0.f;
    #pragma unroll 8
    for (int j = 0; j < 64; ++j) s += sA[r*64+j]*sB[j*64+c];
    sC[i] = s; V2[i] = s;
  }
  __syncthreads();
  for (int i = t; i < 4096; i += 256) sB[i] = Wp[8192+i];
  __syncthreads();
  for (int i = t; i < 4096; i += 256){
    int r = i >> 6, c = i & 63; float s = 0.f;
    #pragma unroll 8
    for (int j = 0; j < 64; ++j) s += sC[r*64+j]*sB[j*64+c];
    V3[i] = s;
  }
}

__global__ void k_ueff(const float* __restrict__ W1, const float* __restrict__ Wp,
                       const float* __restrict__ V2, const float* __restrict__ V3,
                       ushort* __restrict__ W1t){
  __shared__ float col[256];
  int c = blockIdx.x, r = threadIdx.x;
  col[r] = W1[(size_t)r*512 + c];
  __syncthreads();
  int p = r >> 6, i = r & 63;
  float s;
  if (p == 0) s = col[r];
  else {
    const float* V = (p == 1) ? Wp : (p == 2) ? V2 : V3;
    s = 0.f;
    #pragma unroll 8
    for (int j = 0; j < 64; ++j) s += V[i*64+j]*col[p*64+j];
  }
  W1t[c*256 + r] = f2b(s);
}

__global__ void k_w2t(const float* __restrict__ W2, ushort* __restrict__ W2t){
  int col = blockIdx.x, k = threadIdx.x;
  W2t[col*512 + k] = f2b(W2[(size_t)k*64 + col]);
}

// ---------------- bf16 hop aggregation: 8 nodes/wave, lane = (feat-group, node) ----------------
// No cross-lane reduce; per-lane serial accumulation, 4-deep unroll; coalesced writes.
__global__ void k_aggb(const ushort* __restrict__ hb, const int* __restrict__ rbeg,
                       const int* __restrict__ degA, const int* __restrict__ csr,
                       ushort* __restrict__ yb){
  int lane = threadIdx.x & 63;
  int wv = threadIdx.x >> 6;
  int f = lane & 7, s = lane >> 3;
  int n = blockIdx.x*32 + wv*8 + s;              // 3125 blocks * 32 nodes = 100000 exact
  int beg = rbeg[n], dg = degA[n];
  float a[8] = {};
  int i = 0;
  for (; i + 4 <= dg; i += 4){
    int i0 = csr[beg+i], i1 = csr[beg+i+1], i2 = csr[beg+i+2], i3 = csr[beg+i+3];
    bf16x8 v0 = *(const bf16x8*)(hb + (size_t)i0*64 + f*8);
    bf16x8 v1 = *(const bf16x8*)(hb + (size_t)i1*64 + f*8);
    bf16x8 v2 = *(const bf16x8*)(hb + (size_t)i2*64 + f*8);
    bf16x8 v3 = *(const bf16x8*)(hb + (size_t)i3*64 + f*8);
    #pragma unroll
    for (int j = 0; j < 8; ++j)
      a[j] += (b2f((ushort)v0[j]) + b2f((ushort)v1[j]))
            + (b2f((ushort)v2[j]) + b2f((ushort)v3[j]));
  }
  for (; i < dg; ++i){
    int i0 = csr[beg+i];
    bf16x8 v = *(const bf16x8*)(hb + (size_t)i0*64 + f*8);
    #pragma unroll
    for (int j = 0; j < 8; ++j) a[j] += b2f((ushort)v[j]);
  }
  float inv = 1.f / fmaxf((float)dg, 1.f);
  bf16x8 o;
  #pragma unroll
  for (int j = 0; j < 8; ++j) o[j] = (short)f2b(a[j]*inv);
  *(bf16x8*)(yb + (size_t)n*64 + f*8) = o;
}

// ---------------- fused MLP via bf16 MFMA (r9 structure + deep prefetch + setprio) ----------------
__global__ __launch_bounds__(512, 4) void k_mlp(
    const ushort* __restrict__ cat0,              // xb; y1/y2/y3 at +PSTR each
    const ushort* __restrict__ W1t, const float* __restrict__ b1,
    const float* __restrict__ gamma, const float* __restrict__ beta,
    const ushort* __restrict__ W2t, const float* __restrict__ b2,
    float* __restrict__ out){
  constexpr size_t PSTR = 6400000;                // ushorts between concat parts
  __shared__ char lbuf[65536];
  __shared__ float2 s_pair[8][64];
  __shared__ float2 s_stat2[64];

  int tid = threadIdx.x;
  int lane = tid & 63, wv = tid >> 6;
  int l15 = lane & 15, l4 = lane >> 4;

  int bid = blockIdx.x;
  {
    constexpr int NB = 1563, q = NB/8, r = NB%8;
    int xcd = bid & 7, idx = bid >> 3;
    bid = (xcd < r ? xcd*(q+1) : r*(q+1) + (xcd-r)*q) + idx;
  }
  int nbase = bid * 64;

  #pragma unroll
  for (int i = 0; i < 4; ++i){
    int dest = (wv*4 + i)*1024 + lane*16;
    int row = dest >> 9;
    int kbyte = (dest & 511) ^ ((row & 7) << 4);
    const ushort* src = cat0 + (size_t)(kbyte >> 7)*PSTR
                             + (size_t)(nbase + row)*64 + ((kbyte & 127) >> 1);
    __builtin_amdgcn_global_load_lds(
        (const __attribute__((address_space(1))) void*)src,
        (__attribute__((address_space(3))) void*)(lbuf + (wv*4 + i)*1024),
        16, 0, 0);
  }
  __syncthreads();

  #define LOADA(kb, d)                                                          \
    { _Pragma("unroll")                                                         \
      for (int rt = 0; rt < 4; ++rt){                                           \
        int row_ = rt*16 + l15;                                                 \
        d[rt] = *(const bf16x8*)(lbuf + row_*512 +                              \
                 (((kb)*64 + l4*16) ^ ((row_ & 7) << 4)));                      \
      } }
  #define LOADB(kb, d)                                                          \
    { _Pragma("unroll")                                                         \
      for (int ci = 0; ci < 4; ++ci)                                            \
        d[ci] = *(const bf16x8*)(W1t + (size_t)(wv*64 + ci*16 + l15)*256 +      \
                                 (kb)*32 + l4*8); }

  // ---- GEMM1: 2-ahead B prefetch (3-buffer cyclic), setprio around MFMA ----
  f32x4 acc[4][4] = {};
  {
    bf16x8 a[4], b[3][4];
    LOADB(0, b[0]);
    LOADB(1, b[1]);
    #pragma unroll
    for (int kb = 0; kb < 8; ++kb){
      if (kb < 6) LOADB(kb+2, b[(kb+2)%3]);
      LOADA(kb, a);
      __builtin_amdgcn_s_setprio(1);
      #pragma unroll
      for (int rt = 0; rt < 4; ++rt)
        #pragma unroll
        for (int ci = 0; ci < 4; ++ci)
          acc[rt][ci] = __builtin_amdgcn_mfma_f32_16x16x32_bf16(a[rt], b[kb%3][ci], acc[rt][ci], 0, 0, 0);
      __builtin_amdgcn_s_setprio(0);
    }
  }

  float bcol[4], gcol[4], ecol[4];
  #pragma unroll
  for (int ci = 0; ci < 4; ++ci){
    int col = wv*64 + ci*16 + l15;
    bcol[ci] = b1[col]; gcol[ci] = gamma[col]; ecol[ci] = beta[col];
  }
  #pragma unroll
  for (int rt = 0; rt < 4; ++rt)
    #pragma unroll
    for (int ci = 0; ci < 4; ++ci)
      #pragma unroll
      for (int r = 0; r < 4; ++r)
        acc[rt][ci][r] += bcol[ci];

  #pragma unroll
  for (int rt = 0; rt < 4; ++rt){
    #pragma unroll
    for (int r = 0; r < 4; ++r){
      float s = 0.f, q = 0.f;
      #pragma unroll
      for (int ci = 0; ci < 4; ++ci){
        float v = acc[rt][ci][r];
        s += v; q += v*v;
      }
      s = red16(s);
      q = red16(q);
      if (l15 == 0) s_pair[wv][rt*16 + l4*4 + r] = make_float2(s, q);
    }
  }
  __syncthreads();

  if (tid < 64){
    float s = 0.f, q = 0.f;
    #pragma unroll
    for (int w = 0; w < 8; ++w){ float2 p = s_pair[w][tid]; s += p.x; q += p.y; }
    float mu = s * (1.f/512.f);
    float var = q * (1.f/512.f) - mu*mu;
    s_stat2[tid] = make_float2(mu, rsqrtf(var + 1e-5f));
  }
  __syncthreads();

  #pragma unroll
  for (int rt = 0; rt < 4; ++rt){
    #pragma unroll
    for (int r = 0; r < 4; ++r){
      int row = rt*16 + l4*4 + r;
      float2 st = s_stat2[row];
      #pragma unroll
      for (int ci = 0; ci < 4; ++ci){
        float hv = fmaxf((acc[rt][ci][r] - st.x)*st.y*gcol[ci] + ecol[ci], 0.f);
        int col = wv*64 + ci*16 + l15;
        *((ushort*)(lbuf + row*1024 + ((col*2) ^ ((row & 7) << 4)))) = f2b(hv);
      }
    }
  }
  __syncthreads();

  #define LOADH(kb, d)                                                          \
    { _Pragma("unroll")                                                         \
      for (int t = 0; t < 2; ++t){                                              \
        int row_ = (rtb + t)*16 + l15;                                          \
        d[t] = *(const bf16x8*)(lbuf + row_*1024 +                              \
                 (((kb)*64 + l4*16) ^ ((row_ & 7) << 4)));                      \
      } }

  // ---- GEMM2: 3-ahead W2 prefetch (4-buffer cyclic), 1-ahead h ----
  int ct = wv >> 1;
  int rtb = (wv & 1) * 2;
  f32x4 acc2[2] = {};
  const ushort* w2base = W2t + (size_t)(ct*16 + l15)*512 + l4*8;
  {
    bf16x8 hb2[2][2], w2f[4];
    w2f[0] = *(const bf16x8*)(w2base);
    w2f[1] = *(const bf16x8*)(w2base + 32);
    w2f[2] = *(const bf16x8*)(w2base + 64);
    LOADH(0, hb2[0]);
    #pragma unroll
    for (int kb = 0; kb < 16; ++kb){
      if (kb < 13) w2f[(kb+3)&3] = *(const bf16x8*)(w2base + (kb+3)*32);
      if (kb < 15) LOADH(kb+1, hb2[(kb+1)&1]);
      __builtin_amdgcn_s_setprio(1);
      acc2[0] = __builtin_amdgcn_mfma_f32_16x16x32_bf16(hb2[kb&1][0], w2f[kb&3], acc2[0], 0, 0, 0);
      acc2[1] = __builtin_amdgcn_mfma_f32_16x16x32_bf16(hb2[kb&1][1], w2f[kb&3], acc2[1], 0, 0, 0);
      __builtin_amdgcn_s_setprio(0);
    }
  }

  float b2v = b2[ct*16 + l15];
  #pragma unroll
  for (int t = 0; t < 2; ++t){
    #pragma unroll
    for (int r = 0; r < 4; ++r){
      int row = (rtb + t)*16 + l4*4 + r;
      if (nbase + row < NN)
        out[(size_t)(nbase + row)*64 + ct*16 + l15] = acc2[t][r] + b2v;
    }
  }
  #undef LOADA
  #undef LOADB
  #undef LOADH
}

extern "C" void kernel_launch(void* const* d_in, const int* in_sizes, int n_in,
                              void* d_out, int out_size, void* d_ws, size_t ws_size,
                              hipStream_t stream){
  const float* x     = (const float*)d_in[0];
  const int*   eidx  = (const int*)d_in[1];
  const float* wprop = (const float*)d_in[2];
  const float* W1    = (const float*)d_in[3];
  const float* b1    = (const float*)d_in[4];
  const float* gamma = (const float*)d_in[5];
  const float* beta  = (const float*)d_in[6];
  const float* W2    = (const float*)d_in[7];
  const float* b2    = (const float*)d_in[8];
  float* out = (float*)d_out;
  const int* srcA = eidx;
  const int* dstA = eidx + NE;

  char* ws = (char*)d_ws;
  int*    rbeg   = (int*)(ws);                  //   400,000 -> pad   400,384
  int*    degA   = (int*)(ws +      400384);    //   400,000 -> pad   800,768
  ushort* W1t    = (ushort*)(ws +   800768);    //   262,144 ->     1,062,912
  ushort* W2t    = (ushort*)(ws +  1062912);    //    65,536 ->     1,128,448
  float*  V2     = (float*)(ws +   1128448);    //    16,384 ->     1,144,832
  float*  V3     = (float*)(ws +   1144832);    //    16,384 ->     1,161,216
  int*    bukcur = (int*)(ws +     1161216);    //       784 -> pad 1,162,240
  int*    csr    = (int*)(ws +     1162240);    // 8,028,160 ->     9,190,400
  int*    ebuf   = (int*)(ws +     9190400);    // 8,028,160 ->    17,218,560
  ushort* xb     = (ushort*)(ws + 17218560);    // 12.8 MB   ->    30,018,560
  ushort* y1     = (ushort*)(ws + 30018560);    // 12.8 MB   ->    42,818,560
  ushort* y2     = (ushort*)(ws + 42818560);    // 12.8 MB   ->    55,618,560
  ushort* y3     = (ushort*)(ws + 55618560);    // 12.8 MB   ->    68,418,560

  // ---- CSR build (fixed per-bucket windows; no global scan) ----
  hipMemsetAsync(bukcur, 0, NBUK*sizeof(int), stream);
  k_part1<<<256, 512, 0, stream>>>(srcA, dstA, bukcur, ebuf, x, xb);
  k_bfinal<<<NBUK, 512, 0, stream>>>(ebuf, bukcur, rbeg, degA, csr);

  // ---- weight prep ----
  k_vchain<<<1, 256, 0, stream>>>(wprop, V2, V3);
  k_ueff<<<512, 256, 0, stream>>>(W1, wprop, V2, V3, W1t);
  k_w2t<<<64, 512, 0, stream>>>(W2, W2t);

  // ---- 3 hops ----
  k_aggb<<<3125, 256, 0, stream>>>(xb, rbeg, degA, csr, y1);
  k_aggb<<<3125, 256, 0, stream>>>(y1, rbeg, degA, csr, y2);
  k_aggb<<<3125, 256, 0, stream>>>(y2, rbeg, degA, csr, y3);

  // ---- fused MLP ----
  k_mlp<<<1563, 512, 0, stream>>>(xb, W1t, b1, gamma, beta, W2t, b2, out);
}

// Round 14
// 261.604 us; speedup vs baseline: 1.2773x; 1.2773x over previous
//
#include <hip/hip_runtime.h>

constexpr int NN = 100000;
constexpr int NE = 1600000;
constexpr int NBUK = 196;            // 512-node buckets: 196*512 = 100352 >= NN
constexpr int ECAP = 10240;          // bucket capacity (E[cnt]=8192, sigma~90)
constexpr int CHUNK = 6250;          // edges per k_part1 block (256 blocks exact)
constexpr int NPT = 13;              // ceil(6250/512)

typedef __attribute__((ext_vector_type(8))) short bf16x8;
typedef __attribute__((ext_vector_type(4))) float f32x4;

__device__ inline ushort f2b(float f){
  uint u = __float_as_uint(f);
  uint r = (u + 0x7FFFu + ((u >> 16) & 1u)) >> 16;
  return (ushort)r;
}
__device__ inline float b2f(ushort u){
  uint v = ((uint)u) << 16;
  return __uint_as_float(v);
}

template<int CTRL>
__device__ inline float dpp_xadd(float v){
  int j = __builtin_amdgcn_update_dpp(0, __float_as_int(v), CTRL, 0xF, 0xF, true);
  return v + __int_as_float(j);
}
__device__ inline float red16(float v){
  v = dpp_xadd<0xB1>(v);
  v = dpp_xadd<0x4E>(v);
  v = dpp_xadd<0x141>(v);
  v = dpp_xadd<0x140>(v);
  return v;
}

// ---------------- CSR build, phase 1: block-local binning (+ xb convert tail) ----------------
__global__ __launch_bounds__(512) void k_part1(const int* __restrict__ srcA,
                                               const int* __restrict__ dstA,
                                               int* __restrict__ bukcur,
                                               int* __restrict__ ebuf,
                                               const float* __restrict__ x,
                                               ushort* __restrict__ xb){
  __shared__ int stage[CHUNK];
  __shared__ unsigned char bstage[CHUNK];
  __shared__ int hist[256];
  __shared__ int lofs[256];
  __shared__ int lcur[NBUK];
  __shared__ int basebuf[NBUK];
  int t = threadIdx.x;
  int cbase = blockIdx.x * CHUNK;

  if (t < 256) hist[t] = 0;
  if (t < NBUK) lcur[t] = 0;
  __syncthreads();

  int pk[NPT], bb[NPT];
  #pragma unroll
  for (int j = 0; j < NPT; ++j){
    int i = t + j*512;
    bb[j] = -1;
    if (i < CHUNK){
      int e = cbase + i;
      int d = dstA[e];
      bb[j] = d >> 9;
      pk[j] = (srcA[e] << 9) | (d & 511);
      atomicAdd(&hist[bb[j]], 1);
    }
  }
  __syncthreads();

  int v = (t < 256) ? hist[t] : 0;
  if (t < 256) lofs[t] = v;
  __syncthreads();
  #pragma unroll
  for (int off = 1; off < 256; off <<= 1){
    int tv = (t < 256 && t >= off) ? lofs[t-off] : 0;
    __syncthreads();
    if (t < 256) lofs[t] += tv;
    __syncthreads();
  }
  if (t < 256) lofs[t] -= v;
  if (t < NBUK) basebuf[t] = atomicAdd(&bukcur[t], v);
  __syncthreads();

  #pragma unroll
  for (int j = 0; j < NPT; ++j){
    if (bb[j] >= 0){
      int p = atomicAdd(&lcur[bb[j]], 1);
      int slot = lofs[bb[j]] + p;
      stage[slot] = pk[j];
      bstage[slot] = (unsigned char)bb[j];
    }
  }
  __syncthreads();

  for (int i = t; i < CHUNK; i += 512){
    int b = bstage[i];
    int j = i - lofs[b];
    int pos = basebuf[b] + j;
    if (pos < ECAP) ebuf[b*ECAP + pos] = stage[i];
  }

  // ---- tail: x -> bf16 (grid-stride over 1.6M float4), independent work ----
  for (int i = blockIdx.x*512 + t; i < NN*16; i += 256*512){
    float4 vv = ((const float4*)x)[i];
    ushort4 o;
    o.x = f2b(vv.x); o.y = f2b(vv.y); o.z = f2b(vv.z); o.w = f2b(vv.w);
    ((ushort4*)xb)[i] = o;
  }
}

// per bucket: LDS count -> scan -> rbeg/deg + compact csr into FIXED window b*ECAP
__global__ __launch_bounds__(512) void k_bfinal(const int* __restrict__ ebuf,
                                                const int* __restrict__ bukcur,
                                                int* __restrict__ rbeg,
                                                int* __restrict__ degA,
                                                int* __restrict__ csr){
  __shared__ int lcnt[512];
  __shared__ int lscan[512];
  __shared__ int lcur[512];
  int b = blockIdx.x, t = threadIdx.x;
  int cnt = bukcur[b]; if (cnt > ECAP) cnt = ECAP;
  int base = b*ECAP, gbase = b*ECAP;

  lcnt[t] = 0; lcur[t] = 0;
  __syncthreads();
  for (int i = t; i < cnt; i += 512) atomicAdd(&lcnt[ebuf[base+i] & 511], 1);
  __syncthreads();
  int v = lcnt[t];
  lscan[t] = v; __syncthreads();
  #pragma unroll
  for (int off = 1; off < 512; off <<= 1){
    int tv = (t >= off) ? lscan[t-off] : 0;
    __syncthreads();
    lscan[t] += tv;
    __syncthreads();
  }
  int excl = lscan[t] - v;
  lcnt[t] = excl;
  int node = b*512 + t;
  if (node < NN){ rbeg[node] = gbase + excl; degA[node] = v; }
  __syncthreads();
  for (int i = t; i < cnt; i += 512){
    int p = ebuf[base+i];
    int d = p & 511;
    int pos = atomicAdd(&lcur[d], 1);
    csr[gbase + lcnt[d] + pos] = p >> 9;
  }
}

// ---------------- effective-weight prep ----------------
__global__ void k_vchain(const float* __restrict__ Wp, float* __restrict__ V2,
                         float* __restrict__ V3){
  __shared__ float sA[4096], sB[4096], sC[4096];
  int t = threadIdx.x;
  for (int i = t; i < 4096; i += 256){ sA[i] = Wp[i]; sB[i] = Wp[4096+i]; }
  __syncthreads();
  for (int i = t; i < 4096; i += 256){
    int r = i >> 6, c = i & 63; float s = 0.f;
    #pragma unroll 8
    for (int j = 0; j < 64; ++j) s += sA[r*64+j]*sB[j*64+c];
    sC[i] = s; V2[i] = s;
  }
  __syncthreads();
  for (int i = t; i < 4096; i += 256) sB[i] = Wp[8192+i];
  __syncthreads();
  for (int i = t; i < 4096; i += 256){
    int r = i >> 6, c = i & 63; float s = 0.f;
    #pragma unroll 8
    for (int j = 0; j < 64; ++j) s += sC[r*64+j]*sB[j*64+c];
    V3[i] = s;
  }
}

__global__ void k_ueff(const float* __restrict__ W1, const float* __restrict__ Wp,
                       const float* __restrict__ V2, const float* __restrict__ V3,
                       ushort* __restrict__ W1t){
  __shared__ float col[256];
  int c = blockIdx.x, r = threadIdx.x;
  col[r] = W1[(size_t)r*512 + c];
  __syncthreads();
  int p = r >> 6, i = r & 63;
  float s;
  if (p == 0) s = col[r];
  else {
    const float* V = (p == 1) ? Wp : (p == 2) ? V2 : V3;
    s = 0.f;
    #pragma unroll 8
    for (int j = 0; j < 64; ++j) s += V[i*64+j]*col[p*64+j];
  }
  W1t[c*256 + r] = f2b(s);
}

__global__ void k_w2t(const float* __restrict__ W2, ushort* __restrict__ W2t){
  int col = blockIdx.x, k = threadIdx.x;
  W2t[col*512 + k] = f2b(W2[(size_t)k*64 + col]);
}

// ---------------- bf16 hop aggregation: 8 nodes/wave, lane = (feat-group, node) ----------------
// No cross-lane reduce; per-lane serial accumulation, 2-deep unroll; coalesced writes.
__global__ void k_aggb(const ushort* __restrict__ hb, const int* __restrict__ rbeg,
                       const int* __restrict__ degA, const int* __restrict__ csr,
                       ushort* __restrict__ yb){
  int lane = threadIdx.x & 63;
  int wv = threadIdx.x >> 6;
  int f = lane & 7, s = lane >> 3;
  int n = blockIdx.x*32 + wv*8 + s;              // 3125 blocks * 32 nodes = 100000 exact
  int beg = rbeg[n], dg = degA[n];
  float a[8] = {};
  int i = 0;
  for (; i + 2 <= dg; i += 2){
    int i0 = csr[beg+i], i1 = csr[beg+i+1];
    bf16x8 v0 = *(const bf16x8*)(hb + (size_t)i0*64 + f*8);
    bf16x8 v1 = *(const bf16x8*)(hb + (size_t)i1*64 + f*8);
    #pragma unroll
    for (int j = 0; j < 8; ++j)
      a[j] += b2f((ushort)v0[j]) + b2f((ushort)v1[j]);
  }
  if (i < dg){
    int i0 = csr[beg+i];
    bf16x8 v = *(const bf16x8*)(hb + (size_t)i0*64 + f*8);
    #pragma unroll
    for (int j = 0; j < 8; ++j) a[j] += b2f((ushort)v[j]);
  }
  float inv = 1.f / fmaxf((float)dg, 1.f);
  bf16x8 o;
  #pragma unroll
  for (int j = 0; j < 8; ++j) o[j] = (short)f2b(a[j]*inv);
  *(bf16x8*)(yb + (size_t)n*64 + f*8) = o;
}

// ---------------- fused MLP via bf16 MFMA (round-12 structure + setprio only) ----------------
__global__ __launch_bounds__(512, 4) void k_mlp(
    const ushort* __restrict__ cat0,              // xb; y1/y2/y3 at +PSTR each
    const ushort* __restrict__ W1t, const float* __restrict__ b1,
    const float* __restrict__ gamma, const float* __restrict__ beta,
    const ushort* __restrict__ W2t, const float* __restrict__ b2,
    float* __restrict__ out){
  constexpr size_t PSTR = 6400000;                // ushorts between concat parts
  __shared__ char lbuf[65536];
  __shared__ float2 s_pair[8][64];
  __shared__ float2 s_stat2[64];

  int tid = threadIdx.x;
  int lane = tid & 63, wv = tid >> 6;
  int l15 = lane & 15, l4 = lane >> 4;

  int bid = blockIdx.x;
  {
    constexpr int NB = 1563, q = NB/8, r = NB%8;
    int xcd = bid & 7, idx = bid >> 3;
    bid = (xcd < r ? xcd*(q+1) : r*(q+1) + (xcd-r)*q) + idx;
  }
  int nbase = bid * 64;

  #pragma unroll
  for (int i = 0; i < 4; ++i){
    int dest = (wv*4 + i)*1024 + lane*16;
    int row = dest >> 9;
    int kbyte = (dest & 511) ^ ((row & 7) << 4);
    const ushort* src = cat0 + (size_t)(kbyte >> 7)*PSTR
                             + (size_t)(nbase + row)*64 + ((kbyte & 127) >> 1);
    __builtin_amdgcn_global_load_lds(
        (const __attribute__((address_space(1))) void*)src,
        (__attribute__((address_space(3))) void*)(lbuf + (wv*4 + i)*1024),
        16, 0, 0);
  }
  __syncthreads();

  #define LOADA(kb, d)                                                          \
    { _Pragma("unroll")                                                         \
      for (int rt = 0; rt < 4; ++rt){                                           \
        int row_ = rt*16 + l15;                                                 \
        d[rt] = *(const bf16x8*)(lbuf + row_*512 +                              \
                 (((kb)*64 + l4*16) ^ ((row_ & 7) << 4)));                      \
      } }
  #define LOADB(kb, d)                                                          \
    { _Pragma("unroll")                                                         \
      for (int ci = 0; ci < 4; ++ci)                                            \
        d[ci] = *(const bf16x8*)(W1t + (size_t)(wv*64 + ci*16 + l15)*256 +      \
                                 (kb)*32 + l4*8); }

  f32x4 acc[4][4] = {};
  bf16x8 a[4], b[2][4];
  LOADB(0, b[0]);
  #pragma unroll
  for (int kb = 0; kb < 8; ++kb){
    int cur = kb & 1, nxt = cur ^ 1;
    if (kb < 7) LOADB(kb+1, b[nxt]);
    LOADA(kb, a);
    __builtin_amdgcn_s_setprio(1);
    #pragma unroll
    for (int rt = 0; rt < 4; ++rt)
      #pragma unroll
      for (int ci = 0; ci < 4; ++ci)
        acc[rt][ci] = __builtin_amdgcn_mfma_f32_16x16x32_bf16(a[rt], b[cur][ci], acc[rt][ci], 0, 0, 0);
    __builtin_amdgcn_s_setprio(0);
  }

  float bcol[4], gcol[4], ecol[4];
  #pragma unroll
  for (int ci = 0; ci < 4; ++ci){
    int col = wv*64 + ci*16 + l15;
    bcol[ci] = b1[col]; gcol[ci] = gamma[col]; ecol[ci] = beta[col];
  }
  #pragma unroll
  for (int rt = 0; rt < 4; ++rt)
    #pragma unroll
    for (int ci = 0; ci < 4; ++ci)
      #pragma unroll
      for (int r = 0; r < 4; ++r)
        acc[rt][ci][r] += bcol[ci];

  #pragma unroll
  for (int rt = 0; rt < 4; ++rt){
    #pragma unroll
    for (int r = 0; r < 4; ++r){
      float s = 0.f, q = 0.f;
      #pragma unroll
      for (int ci = 0; ci < 4; ++ci){
        float v = acc[rt][ci][r];
        s += v; q += v*v;
      }
      s = red16(s);
      q = red16(q);
      if (l15 == 0) s_pair[wv][rt*16 + l4*4 + r] = make_float2(s, q);
    }
  }
  __syncthreads();

  if (tid < 64){
    float s = 0.f, q = 0.f;
    #pragma unroll
    for (int w = 0; w < 8; ++w){ float2 p = s_pair[w][tid]; s += p.x; q += p.y; }
    float mu = s * (1.f/512.f);
    float var = q * (1.f/512.f) - mu*mu;
    s_stat2[tid] = make_float2(mu, rsqrtf(var + 1e-5f));
  }
  __syncthreads();

  #pragma unroll
  for (int rt = 0; rt < 4; ++rt){
    #pragma unroll
    for (int r = 0; r < 4; ++r){
      int row = rt*16 + l4*4 + r;
      float2 st = s_stat2[row];
      #pragma unroll
      for (int ci = 0; ci < 4; ++ci){
        float hv = fmaxf((acc[rt][ci][r] - st.x)*st.y*gcol[ci] + ecol[ci], 0.f);
        int col = wv*64 + ci*16 + l15;
        *((ushort*)(lbuf + row*1024 + ((col*2) ^ ((row & 7) << 4)))) = f2b(hv);
      }
    }
  }
  __syncthreads();

  #define LOADH(kb, d)                                                          \
    { _Pragma("unroll")                                                         \
      for (int t = 0; t < 2; ++t){                                              \
        int row_ = (rtb + t)*16 + l15;                                          \
        d[t] = *(const bf16x8*)(lbuf + row_*1024 +                              \
                 (((kb)*64 + l4*16) ^ ((row_ & 7) << 4)));                      \
      } }

  int ct = wv >> 1;
  int rtb = (wv & 1) * 2;
  f32x4 acc2[2] = {};
  const ushort* w2base = W2t + (size_t)(ct*16 + l15)*512 + l4*8;
  bf16x8 hb2[2][2], w2f[2];
  w2f[0] = *(const bf16x8*)(w2base);
  LOADH(0, hb2[0]);
  #pragma unroll
  for (int kb = 0; kb < 16; ++kb){
    int cur = kb & 1, nxt = cur ^ 1;
    if (kb < 15){
      w2f[nxt] = *(const bf16x8*)(w2base + (kb+1)*32);
      LOADH(kb+1, hb2[nxt]);
    }
    __builtin_amdgcn_s_setprio(1);
    acc2[0] = __builtin_amdgcn_mfma_f32_16x16x32_bf16(hb2[cur][0], w2f[cur], acc2[0], 0, 0, 0);
    acc2[1] = __builtin_amdgcn_mfma_f32_16x16x32_bf16(hb2[cur][1], w2f[cur], acc2[1], 0, 0, 0);
    __builtin_amdgcn_s_setprio(0);
  }

  float b2v = b2[ct*16 + l15];
  #pragma unroll
  for (int t = 0; t < 2; ++t){
    #pragma unroll
    for (int r = 0; r < 4; ++r){
      int row = (rtb + t)*16 + l4*4 + r;
      if (nbase + row < NN)
        out[(size_t)(nbase + row)*64 + ct*16 + l15] = acc2[t][r] + b2v;
    }
  }
  #undef LOADA
  #undef LOADB
  #undef LOADH
}

extern "C" void kernel_launch(void* const* d_in, const int* in_sizes, int n_in,
                              void* d_out, int out_size, void* d_ws, size_t ws_size,
                              hipStream_t stream){
  const float* x     = (const float*)d_in[0];
  const int*   eidx  = (const int*)d_in[1];
  const float* wprop = (const float*)d_in[2];
  const float* W1    = (const float*)d_in[3];
  const float* b1    = (const float*)d_in[4];
  const float* gamma = (const float*)d_in[5];
  const float* beta  = (const float*)d_in[6];
  const float* W2    = (const float*)d_in[7];
  const float* b2    = (const float*)d_in[8];
  float* out = (float*)d_out;
  const int* srcA = eidx;
  const int* dstA = eidx + NE;

  char* ws = (char*)d_ws;
  int*    rbeg   = (int*)(ws);                  //   400,000 -> pad   400,384
  int*    degA   = (int*)(ws +      400384);    //   400,000 -> pad   800,768
  ushort* W1t    = (ushort*)(ws +   800768);    //   262,144 ->     1,062,912
  ushort* W2t    = (ushort*)(ws +  1062912);    //    65,536 ->     1,128,448
  float*  V2     = (float*)(ws +   1128448);    //    16,384 ->     1,144,832
  float*  V3     = (float*)(ws +   1144832);    //    16,384 ->     1,161,216
  int*    bukcur = (int*)(ws +     1161216);    //       784 -> pad 1,162,240
  int*    csr    = (int*)(ws +     1162240);    // 8,028,160 ->     9,190,400
  int*    ebuf   = (int*)(ws +     9190400);    // 8,028,160 ->    17,218,560
  ushort* xb     = (ushort*)(ws + 17218560);    // 12.8 MB   ->    30,018,560
  ushort* y1     = (ushort*)(ws + 30018560);    // 12.8 MB   ->    42,818,560
  ushort* y2     = (ushort*)(ws + 42818560);    // 12.8 MB   ->    55,618,560
  ushort* y3     = (ushort*)(ws + 55618560);    // 12.8 MB   ->    68,418,560

  // ---- CSR build (fixed per-bucket windows; no global scan) ----
  hipMemsetAsync(bukcur, 0, NBUK*sizeof(int), stream);
  k_part1<<<256, 512, 0, stream>>>(srcA, dstA, bukcur, ebuf, x, xb);
  k_bfinal<<<NBUK, 512, 0, stream>>>(ebuf, bukcur, rbeg, degA, csr);

  // ---- weight prep ----
  k_vchain<<<1, 256, 0, stream>>>(wprop, V2, V3);
  k_ueff<<<512, 256, 0, stream>>>(W1, wprop, V2, V3, W1t);
  k_w2t<<<64, 512, 0, stream>>>(W2, W2t);

  // ---- 3 hops ----
  k_aggb<<<3125, 256, 0, stream>>>(xb, rbeg, degA, csr, y1);
  k_aggb<<<3125, 256, 0, stream>>>(y1, rbeg, degA, csr, y2);
  k_aggb<<<3125, 256, 0, stream>>>(y2, rbeg, degA, csr, y3);

  // ---- fused MLP ----
  k_mlp<<<1563, 512, 0, stream>>>(xb, W1t, b1, gamma, beta, W2t, b2, out);
}

// Round 15
// 243.866 us; speedup vs baseline: 1.3703x; 1.0727x over previous
//
#include <hip/hip_runtime.h>

constexpr int NN = 100000;
constexpr int NE = 1600000;
constexpr int NBUK = 196;            // 512-node buckets: 196*512 = 100352 >= NN
constexpr int ECAP = 10240;          // bucket capacity (E[cnt]=8192, sigma~90)
constexpr int CHUNK = 6250;          // edges per k_part1 block (256 blocks exact)
constexpr int NPT = 13;              // ceil(6250/512)

typedef __attribute__((ext_vector_type(8))) short bf16x8;
typedef __attribute__((ext_vector_type(4))) float f32x4;

__device__ inline ushort f2b(float f){
  uint u = __float_as_uint(f);
  uint r = (u + 0x7FFFu + ((u >> 16) & 1u)) >> 16;
  return (ushort)r;
}
__device__ inline float b2f(ushort u){
  uint v = ((uint)u) << 16;
  return __uint_as_float(v);
}

template<int CTRL>
__device__ inline float dpp_xadd(float v){
  int j = __builtin_amdgcn_update_dpp(0, __float_as_int(v), CTRL, 0xF, 0xF, true);
  return v + __int_as_float(j);
}
__device__ inline float red16(float v){
  v = dpp_xadd<0xB1>(v);
  v = dpp_xadd<0x4E>(v);
  v = dpp_xadd<0x141>(v);
  v = dpp_xadd<0x140>(v);
  return v;
}

// ---------------- CSR build, phase 1: block-local binning (+ xb convert tail) ----------------
__global__ __launch_bounds__(512) void k_part1(const int* __restrict__ srcA,
                                               const int* __restrict__ dstA,
                                               int* __restrict__ bukcur,
                                               int* __restrict__ ebuf,
                                               const float* __restrict__ x,
                                               ushort* __restrict__ xb){
  __shared__ int stage[CHUNK];
  __shared__ unsigned char bstage[CHUNK];
  __shared__ int hist[256];
  __shared__ int lofs[256];
  __shared__ int lcur[NBUK];
  __shared__ int basebuf[NBUK];
  int t = threadIdx.x;
  int cbase = blockIdx.x * CHUNK;

  if (t < 256) hist[t] = 0;
  if (t < NBUK) lcur[t] = 0;
  __syncthreads();

  int pk[NPT], bb[NPT];
  #pragma unroll
  for (int j = 0; j < NPT; ++j){
    int i = t + j*512;
    bb[j] = -1;
    if (i < CHUNK){
      int e = cbase + i;
      int d = dstA[e];
      bb[j] = d >> 9;
      pk[j] = (srcA[e] << 9) | (d & 511);
      atomicAdd(&hist[bb[j]], 1);
    }
  }
  __syncthreads();

  int v = (t < 256) ? hist[t] : 0;
  if (t < 256) lofs[t] = v;
  __syncthreads();
  #pragma unroll
  for (int off = 1; off < 256; off <<= 1){
    int tv = (t < 256 && t >= off) ? lofs[t-off] : 0;
    __syncthreads();
    if (t < 256) lofs[t] += tv;
    __syncthreads();
  }
  if (t < 256) lofs[t] -= v;
  if (t < NBUK) basebuf[t] = atomicAdd(&bukcur[t], v);
  __syncthreads();

  #pragma unroll
  for (int j = 0; j < NPT; ++j){
    if (bb[j] >= 0){
      int p = atomicAdd(&lcur[bb[j]], 1);
      int slot = lofs[bb[j]] + p;
      stage[slot] = pk[j];
      bstage[slot] = (unsigned char)bb[j];
    }
  }
  __syncthreads();

  for (int i = t; i < CHUNK; i += 512){
    int b = bstage[i];
    int j = i - lofs[b];
    int pos = basebuf[b] + j;
    if (pos < ECAP) ebuf[b*ECAP + pos] = stage[i];
  }

  // ---- tail: x -> bf16 (grid-stride over 1.6M float4), independent work ----
  for (int i = blockIdx.x*512 + t; i < NN*16; i += 256*512){
    float4 vv = ((const float4*)x)[i];
    ushort4 o;
    o.x = f2b(vv.x); o.y = f2b(vv.y); o.z = f2b(vv.z); o.w = f2b(vv.w);
    ((ushort4*)xb)[i] = o;
  }
}

// per bucket: LDS count -> scan -> rbeg/deg + compact csr into FIXED window b*ECAP
__global__ __launch_bounds__(512) void k_bfinal(const int* __restrict__ ebuf,
                                                const int* __restrict__ bukcur,
                                                int* __restrict__ rbeg,
                                                int* __restrict__ degA,
                                                int* __restrict__ csr){
  __shared__ int lcnt[512];
  __shared__ int lscan[512];
  __shared__ int lcur[512];
  int b = blockIdx.x, t = threadIdx.x;
  int cnt = bukcur[b]; if (cnt > ECAP) cnt = ECAP;
  int base = b*ECAP, gbase = b*ECAP;

  lcnt[t] = 0; lcur[t] = 0;
  __syncthreads();
  for (int i = t; i < cnt; i += 512) atomicAdd(&lcnt[ebuf[base+i] & 511], 1);
  __syncthreads();
  int v = lcnt[t];
  lscan[t] = v; __syncthreads();
  #pragma unroll
  for (int off = 1; off < 512; off <<= 1){
    int tv = (t >= off) ? lscan[t-off] : 0;
    __syncthreads();
    lscan[t] += tv;
    __syncthreads();
  }
  int excl = lscan[t] - v;
  lcnt[t] = excl;
  int node = b*512 + t;
  if (node < NN){ rbeg[node] = gbase + excl; degA[node] = v; }
  __syncthreads();
  for (int i = t; i < cnt; i += 512){
    int p = ebuf[base+i];
    int d = p & 511;
    int pos = atomicAdd(&lcur[d], 1);
    csr[gbase + lcnt[d] + pos] = p >> 9;
  }
}

// ---------------- merged weight prep: blocks 0..511 = W1t col, 512..575 = W2t ----------------
// V3 dependency removed algebraically: V3[i]·c192 = V2[i]·(Wp2·c192)  (u-vector in LDS)
__global__ __launch_bounds__(256) void k_wprep(const float* __restrict__ Wp,
                                               const float* __restrict__ W1,
                                               const float* __restrict__ W2,
                                               ushort* __restrict__ W1t,
                                               ushort* __restrict__ W2t){
  int b = blockIdx.x, t = threadIdx.x;
  if (b >= 512){
    int col = b - 512;
    for (int k = t; k < 512; k += 256)
      W2t[col*512 + k] = f2b(W2[(size_t)k*64 + col]);
    return;
  }
  __shared__ float sA[4096];     // Wp0
  __shared__ float sB[4096];     // Wp1, then Wp2
  __shared__ float sV2[4096];    // Wp0@Wp1
  __shared__ float col[256];
  __shared__ float u[64];        // Wp2 @ col[192:256]

  for (int i = t; i < 4096; i += 256){ sA[i] = Wp[i]; sB[i] = Wp[4096+i]; }
  __syncthreads();
  for (int i = t; i < 4096; i += 256){
    int r = i >> 6, c = i & 63; float s = 0.f;
    #pragma unroll 8
    for (int j = 0; j < 64; ++j) s += sA[r*64+j]*sB[j*64+c];
    sV2[i] = s;
  }
  __syncthreads();
  for (int i = t; i < 4096; i += 256) sB[i] = Wp[8192+i];   // Wp2
  col[t] = W1[(size_t)t*512 + b];
  __syncthreads();
  if (t < 64){
    float s = 0.f;
    #pragma unroll 8
    for (int j = 0; j < 64; ++j) s += sB[t*64+j]*col[192+j];
    u[t] = s;
  }
  __syncthreads();

  int p = t >> 6, i2 = t & 63;
  float s;
  if (p == 0) s = col[t];
  else if (p == 1){
    s = 0.f;
    #pragma unroll 8
    for (int j = 0; j < 64; ++j) s += sA[i2*64+j]*col[64+j];
  } else if (p == 2){
    s = 0.f;
    #pragma unroll 8
    for (int j = 0; j < 64; ++j) s += sV2[i2*64+j]*col[128+j];
  } else {
    s = 0.f;
    #pragma unroll 8
    for (int j = 0; j < 64; ++j) s += sV2[i2*64+j]*u[j];
  }
  W1t[b*256 + t] = f2b(s);
}

// ---------------- bf16 hop aggregation: 8 nodes/wave, per-lane serial, 4-deep ----------------
__global__ void k_aggb(const ushort* __restrict__ hb, const int* __restrict__ rbeg,
                       const int* __restrict__ degA, const int* __restrict__ csr,
                       ushort* __restrict__ yb){
  int lane = threadIdx.x & 63;
  int wv = threadIdx.x >> 6;
  int f = lane & 7, s = lane >> 3;
  int n = blockIdx.x*32 + wv*8 + s;              // 3125 blocks * 32 nodes = 100000 exact
  int beg = rbeg[n], dg = degA[n];
  float a[8] = {};
  int i = 0;
  for (; i + 4 <= dg; i += 4){
    int i0 = csr[beg+i], i1 = csr[beg+i+1], i2 = csr[beg+i+2], i3 = csr[beg+i+3];
    bf16x8 v0 = *(const bf16x8*)(hb + (size_t)i0*64 + f*8);
    bf16x8 v1 = *(const bf16x8*)(hb + (size_t)i1*64 + f*8);
    bf16x8 v2 = *(const bf16x8*)(hb + (size_t)i2*64 + f*8);
    bf16x8 v3 = *(const bf16x8*)(hb + (size_t)i3*64 + f*8);
    #pragma unroll
    for (int j = 0; j < 8; ++j)
      a[j] += (b2f((ushort)v0[j]) + b2f((ushort)v1[j]))
            + (b2f((ushort)v2[j]) + b2f((ushort)v3[j]));
  }
  for (; i < dg; ++i){
    int i0 = csr[beg+i];
    bf16x8 v = *(const bf16x8*)(hb + (size_t)i0*64 + f*8);
    #pragma unroll
    for (int j = 0; j < 8; ++j) a[j] += b2f((ushort)v[j]);
  }
  float inv = 1.f / fmaxf((float)dg, 1.f);
  bf16x8 o;
  #pragma unroll
  for (int j = 0; j < 8; ++j) o[j] = (short)f2b(a[j]*inv);
  *(bf16x8*)(yb + (size_t)n*64 + f*8) = o;
}

// ---------------- fused MLP via bf16 MFMA (round-14 known-good: r12 + setprio) ----------------
__global__ __launch_bounds__(512, 4) void k_mlp(
    const ushort* __restrict__ cat0,              // xb; y1/y2/y3 at +PSTR each
    const ushort* __restrict__ W1t, const float* __restrict__ b1,
    const float* __restrict__ gamma, const float* __restrict__ beta,
    const ushort* __restrict__ W2t, const float* __restrict__ b2,
    float* __restrict__ out){
  constexpr size_t PSTR = 6400000;                // ushorts between concat parts
  __shared__ char lbuf[65536];
  __shared__ float2 s_pair[8][64];
  __shared__ float2 s_stat2[64];

  int tid = threadIdx.x;
  int lane = tid & 63, wv = tid >> 6;
  int l15 = lane & 15, l4 = lane >> 4;

  int bid = blockIdx.x;
  {
    constexpr int NB = 1563, q = NB/8, r = NB%8;
    int xcd = bid & 7, idx = bid >> 3;
    bid = (xcd < r ? xcd*(q+1) : r*(q+1) + (xcd-r)*q) + idx;
  }
  int nbase = bid * 64;

  #pragma unroll
  for (int i = 0; i < 4; ++i){
    int dest = (wv*4 + i)*1024 + lane*16;
    int row = dest >> 9;
    int kbyte = (dest & 511) ^ ((row & 7) << 4);
    const ushort* src = cat0 + (size_t)(kbyte >> 7)*PSTR
                             + (size_t)(nbase + row)*64 + ((kbyte & 127) >> 1);
    __builtin_amdgcn_global_load_lds(
        (const __attribute__((address_space(1))) void*)src,
        (__attribute__((address_space(3))) void*)(lbuf + (wv*4 + i)*1024),
        16, 0, 0);
  }
  __syncthreads();

  #define LOADA(kb, d)                                                          \
    { _Pragma("unroll")                                                         \
      for (int rt = 0; rt < 4; ++rt){                                           \
        int row_ = rt*16 + l15;                                                 \
        d[rt] = *(const bf16x8*)(lbuf + row_*512 +                              \
                 (((kb)*64 + l4*16) ^ ((row_ & 7) << 4)));                      \
      } }
  #define LOADB(kb, d)                                                          \
    { _Pragma("unroll")                                                         \
      for (int ci = 0; ci < 4; ++ci)                                            \
        d[ci] = *(const bf16x8*)(W1t + (size_t)(wv*64 + ci*16 + l15)*256 +      \
                                 (kb)*32 + l4*8); }

  f32x4 acc[4][4] = {};
  bf16x8 a[4], b[2][4];
  LOADB(0, b[0]);
  #pragma unroll
  for (int kb = 0; kb < 8; ++kb){
    int cur = kb & 1, nxt = cur ^ 1;
    if (kb < 7) LOADB(kb+1, b[nxt]);
    LOADA(kb, a);
    __builtin_amdgcn_s_setprio(1);
    #pragma unroll
    for (int rt = 0; rt < 4; ++rt)
      #pragma unroll
      for (int ci = 0; ci < 4; ++ci)
        acc[rt][ci] = __builtin_amdgcn_mfma_f32_16x16x32_bf16(a[rt], b[cur][ci], acc[rt][ci], 0, 0, 0);
    __builtin_amdgcn_s_setprio(0);
  }

  float bcol[4], gcol[4], ecol[4];
  #pragma unroll
  for (int ci = 0; ci < 4; ++ci){
    int col = wv*64 + ci*16 + l15;
    bcol[ci] = b1[col]; gcol[ci] = gamma[col]; ecol[ci] = beta[col];
  }
  #pragma unroll
  for (int rt = 0; rt < 4; ++rt)
    #pragma unroll
    for (int ci = 0; ci < 4; ++ci)
      #pragma unroll
      for (int r = 0; r < 4; ++r)
        acc[rt][ci][r] += bcol[ci];

  #pragma unroll
  for (int rt = 0; rt < 4; ++rt){
    #pragma unroll
    for (int r = 0; r < 4; ++r){
      float s = 0.f, q = 0.f;
      #pragma unroll
      for (int ci = 0; ci < 4; ++ci){
        float v = acc[rt][ci][r];
        s += v; q += v*v;
      }
      s = red16(s);
      q = red16(q);
      if (l15 == 0) s_pair[wv][rt*16 + l4*4 + r] = make_float2(s, q);
    }
  }
  __syncthreads();

  if (tid < 64){
    float s = 0.f, q = 0.f;
    #pragma unroll
    for (int w = 0; w < 8; ++w){ float2 p = s_pair[w][tid]; s += p.x; q += p.y; }
    float mu = s * (1.f/512.f);
    float var = q * (1.f/512.f) - mu*mu;
    s_stat2[tid] = make_float2(mu, rsqrtf(var + 1e-5f));
  }
  __syncthreads();

  #pragma unroll
  for (int rt = 0; rt < 4; ++rt){
    #pragma unroll
    for (int r = 0; r < 4; ++r){
      int row = rt*16 + l4*4 + r;
      float2 st = s_stat2[row];
      #pragma unroll
      for (int ci = 0; ci < 4; ++ci){
        float hv = fmaxf((acc[rt][ci][r] - st.x)*st.y*gcol[ci] + ecol[ci], 0.f);
        int col = wv*64 + ci*16 + l15;
        *((ushort*)(lbuf + row*1024 + ((col*2) ^ ((row & 7) << 4)))) = f2b(hv);
      }
    }
  }
  __syncthreads();

  #define LOADH(kb, d)                                                          \
    { _Pragma("unroll")                                                         \
      for (int t = 0; t < 2; ++t){                                              \
        int row_ = (rtb + t)*16 + l15;                                          \
        d[t] = *(const bf16x8*)(lbuf + row_*1024 +                              \
                 (((kb)*64 + l4*16) ^ ((row_ & 7) << 4)));                      \
      } }

  int ct = wv >> 1;
  int rtb = (wv & 1) * 2;
  f32x4 acc2[2] = {};
  const ushort* w2base = W2t + (size_t)(ct*16 + l15)*512 + l4*8;
  bf16x8 hb2[2][2], w2f[2];
  w2f[0] = *(const bf16x8*)(w2base);
  LOADH(0, hb2[0]);
  #pragma unroll
  for (int kb = 0; kb < 16; ++kb){
    int cur = kb & 1, nxt = cur ^ 1;
    if (kb < 15){
      w2f[nxt] = *(const bf16x8*)(w2base + (kb+1)*32);
      LOADH(kb+1, hb2[nxt]);
    }
    __builtin_amdgcn_s_setprio(1);
    acc2[0] = __builtin_amdgcn_mfma_f32_16x16x32_bf16(hb2[cur][0], w2f[cur], acc2[0], 0, 0, 0);
    acc2[1] = __builtin_amdgcn_mfma_f32_16x16x32_bf16(hb2[cur][1], w2f[cur], acc2[1], 0, 0, 0);
    __builtin_amdgcn_s_setprio(0);
  }

  float b2v = b2[ct*16 + l15];
  #pragma unroll
  for (int t = 0; t < 2; ++t){
    #pragma unroll
    for (int r = 0; r < 4; ++r){
      int row = (rtb + t)*16 + l4*4 + r;
      if (nbase + row < NN)
        out[(size_t)(nbase + row)*64 + ct*16 + l15] = acc2[t][r] + b2v;
    }
  }
  #undef LOADA
  #undef LOADB
  #undef LOADH
}

extern "C" void kernel_launch(void* const* d_in, const int* in_sizes, int n_in,
                              void* d_out, int out_size, void* d_ws, size_t ws_size,
                              hipStream_t stream){
  const float* x     = (const float*)d_in[0];
  const int*   eidx  = (const int*)d_in[1];
  const float* wprop = (const float*)d_in[2];
  const float* W1    = (const float*)d_in[3];
  const float* b1    = (const float*)d_in[4];
  const float* gamma = (const float*)d_in[5];
  const float* beta  = (const float*)d_in[6];
  const float* W2    = (const float*)d_in[7];
  const float* b2    = (const float*)d_in[8];
  float* out = (float*)d_out;
  const int* srcA = eidx;
  const int* dstA = eidx + NE;

  char* ws = (char*)d_ws;
  int*    rbeg   = (int*)(ws);                  //   400,000 -> pad   400,384
  int*    degA   = (int*)(ws +      400384);    //   400,000 -> pad   800,768
  ushort* W1t    = (ushort*)(ws +   800768);    //   262,144 ->     1,062,912
  ushort* W2t    = (ushort*)(ws +  1062912);    //    65,536 ->     1,128,448
  int*    bukcur = (int*)(ws +     1128448);    //       784 -> pad 1,129,472
  int*    csr    = (int*)(ws +     1129472);    // 8,028,160 ->     9,157,632
  int*    ebuf   = (int*)(ws +     9157632);    // 8,028,160 ->    17,185,792
  ushort* xb     = (ushort*)(ws + 17185792);    // 12.8 MB   ->    29,985,792
  ushort* y1     = (ushort*)(ws + 29985792);    // 12.8 MB   ->    42,785,792
  ushort* y2     = (ushort*)(ws + 42785792);    // 12.8 MB   ->    55,585,792
  ushort* y3     = (ushort*)(ws + 55585792);    // 12.8 MB   ->    68,385,792

  // ---- CSR build (fixed per-bucket windows; no global scan) ----
  hipMemsetAsync(bukcur, 0, NBUK*sizeof(int), stream);
  k_part1<<<256, 512, 0, stream>>>(srcA, dstA, bukcur, ebuf, x, xb);
  k_bfinal<<<NBUK, 512, 0, stream>>>(ebuf, bukcur, rbeg, degA, csr);

  // ---- weight prep (single merged launch) ----
  k_wprep<<<576, 256, 0, stream>>>(wprop, W1, W2, W1t, W2t);

  // ---- 3 hops ----
  k_aggb<<<3125, 256, 0, stream>>>(xb, rbeg, degA, csr, y1);
  k_aggb<<<3125, 256, 0, stream>>>(y1, rbeg, degA, csr, y2);
  k_aggb<<<3125, 256, 0, stream>>>(y2, rbeg, degA, csr, y3);

  // ---- fused MLP ----
  k_mlp<<<1563, 512, 0, stream>>>(xb, W1t, b1, gamma, beta, W2t, b2, out);
}